// Round 2
// baseline (329.872 us; speedup 1.0000x reference)
//
#include <hip/hip_runtime.h>
#include <math.h>

#define NROWS 65536
#define DDIM 512
#define NUM_CLASSES 1000
#define NBLOCKS 2048
#define ROWS_PER_WAVE 8   // 2048 blocks * 4 waves * 8 rows = 65536

// zero the 1000 class bins plus the completion counter (ws[1000])
__global__ void CenterLoss_zero_ws(float* __restrict__ ws) {
    int i = threadIdx.x + blockIdx.x * blockDim.x;
    if (i <= NUM_CLASSES) ws[i] = 0.0f;
}

__device__ inline float sqdiff4(float4 a, float4 b) {
    float dx = a.x - b.x, dy = a.y - b.y, dz = a.z - b.z, dw = a.w - b.w;
    return fmaf(dx, dx, fmaf(dy, dy, fmaf(dz, dz, dw * dw)));
}

__global__ __launch_bounds__(256) void CenterLoss_accum(
    const float* __restrict__ x,
    const int* __restrict__ labels,
    const float* __restrict__ centers,
    float* __restrict__ ws,          // [NUM_CLASSES] bins, ws[NUM_CLASSES] = counter
    float* __restrict__ out)
{
    const int lane = threadIdx.x & 63;
    const int wid  = (blockIdx.x << 2) + (threadIdx.x >> 6);
    const int row0 = wid * ROWS_PER_WAVE;

    // batch-fetch this wave's 8 labels once (coalesced, lanes 0..7)
    int mylbl = (lane < ROWS_PER_WAVE) ? labels[row0 + lane] : 0;

#pragma unroll
    for (int k = 0; k < ROWS_PER_WAVE; k += 2) {
        const int l0 = __shfl(mylbl, k,     64);
        const int l1 = __shfl(mylbl, k + 1, 64);

        const float4* __restrict__ xr0 =
            reinterpret_cast<const float4*>(x + (size_t)(row0 + k) * DDIM);
        const float4* __restrict__ xr1 =
            reinterpret_cast<const float4*>(x + (size_t)(row0 + k + 1) * DDIM);
        const float4* __restrict__ cr0 =
            reinterpret_cast<const float4*>(centers + (size_t)l0 * DDIM);
        const float4* __restrict__ cr1 =
            reinterpret_cast<const float4*>(centers + (size_t)l1 * DDIM);

        // issue all 8 loads (128B/lane) before any compute
        const float4 xa0 = xr0[lane], xa1 = xr0[lane + 64];
        const float4 xb0 = xr1[lane], xb1 = xr1[lane + 64];
        const float4 ca0 = cr0[lane], ca1 = cr0[lane + 64];
        const float4 cb0 = cr1[lane], cb1 = cr1[lane + 64];

        float acc0 = sqdiff4(xa0, ca0) + sqdiff4(xa1, ca1);
        float acc1 = sqdiff4(xb0, cb0) + sqdiff4(xb1, cb1);

        // two interleaved 64-lane butterflies (ILP 2)
#pragma unroll
        for (int off = 32; off > 0; off >>= 1) {
            acc0 += __shfl_xor(acc0, off, 64);
            acc1 += __shfl_xor(acc1, off, 64);
        }

        // one atomic instruction, 2 active lanes, 2 different bins
        const float aval = (lane == 0) ? acc0 : acc1;
        const int   abin = (lane == 0) ? l0   : l1;
        if (lane < 2) atomicAdd(&ws[abin], aval);
    }

    // ---- fused finalize: last block to finish reduces the bins ----
    __threadfence();
    __syncthreads();
    __shared__ int is_last;
    if (threadIdx.x == 0) {
        int* counter = reinterpret_cast<int*>(ws + NUM_CLASSES);
        int prev = __hip_atomic_fetch_add(counter, 1, __ATOMIC_ACQ_REL,
                                          __HIP_MEMORY_SCOPE_AGENT);
        is_last = (prev == NBLOCKS - 1);
    }
    __syncthreads();
    if (!is_last) return;

    float s = 0.0f;
    for (int c = threadIdx.x; c < NUM_CLASSES; c += 256) {
        // agent-scope load: safe against cross-XCD L2 staleness
        float v = __hip_atomic_load(&ws[c], __ATOMIC_RELAXED,
                                    __HIP_MEMORY_SCOPE_AGENT);
        s += sqrtf(v);
    }
#pragma unroll
    for (int off = 32; off > 0; off >>= 1)
        s += __shfl_xor(s, off, 64);

    __shared__ float partial[4];
    if (lane == 0) partial[threadIdx.x >> 6] = s;
    __syncthreads();
    if (threadIdx.x == 0)
        out[0] = (partial[0] + partial[1] + partial[2] + partial[3])
                 / (float)NUM_CLASSES;
}

extern "C" void kernel_launch(void* const* d_in, const int* in_sizes, int n_in,
                              void* d_out, int out_size, void* d_ws, size_t ws_size,
                              hipStream_t stream) {
    const float* x       = (const float*)d_in[0];
    const int*   labels  = (const int*)d_in[1];
    const float* centers = (const float*)d_in[2];
    float* out = (float*)d_out;
    float* ws  = (float*)d_ws;

    CenterLoss_zero_ws<<<(NUM_CLASSES + 1 + 255) / 256, 256, 0, stream>>>(ws);
    CenterLoss_accum<<<NBLOCKS, 256, 0, stream>>>(x, labels, centers, ws, out);
}

// Round 3
// 42.852 us; speedup vs baseline: 7.6979x; 7.6979x over previous
//
#include <hip/hip_runtime.h>
#include <math.h>

#define NROWS 65536
#define DDIM 512
#define NUM_CLASSES 1000

// --- kernel 1: zero the 1000 class bins (single block) ---
__global__ __launch_bounds__(256) void CenterLoss_zero_ws(float* __restrict__ ws) {
    for (int i = threadIdx.x; i < NUM_CLASSES; i += 256) ws[i] = 0.0f;
}

__device__ inline float sqdiff4(float4 a, float4 b) {
    float dx = a.x - b.x, dy = a.y - b.y, dz = a.z - b.z, dw = a.w - b.w;
    return fmaf(dx, dx, fmaf(dy, dy, fmaf(dz, dz, dw * dw)));
}

// --- kernel 2: one 64-lane wave per row; block = 4 waves = 4 rows ---
// Plain device-scope atomicAdd (no return, no fences): fire-and-forget f32
// add at the coherence point — off the critical path. Ordering vs finalize
// comes from the kernel-launch boundary, NOT per-block fences (R2 lesson).
__global__ __launch_bounds__(256) void CenterLoss_accum(
    const float* __restrict__ x,
    const int* __restrict__ labels,
    const float* __restrict__ centers,
    float* __restrict__ ws)
{
    const int wave = threadIdx.x >> 6;
    const int lane = threadIdx.x & 63;
    const int row  = (blockIdx.x << 2) + wave;

    const int lbl = labels[row];

    const float4* __restrict__ xr =
        reinterpret_cast<const float4*>(x + (size_t)row * DDIM);
    const float4* __restrict__ cr =
        reinterpret_cast<const float4*>(centers + (size_t)lbl * DDIM);

    // Row = 128 float4. Lane i reads #i and #(i+64): two fully-coalesced
    // 1 KiB wave-transactions of x, two of the (L2-resident) center row.
    const float4 xv0 = xr[lane];
    const float4 xv1 = xr[lane + 64];
    const float4 cv0 = cr[lane];
    const float4 cv1 = cr[lane + 64];

    float acc = sqdiff4(xv0, cv0) + sqdiff4(xv1, cv1);

    // 64-lane butterfly (compiler lowers small offsets to DPP)
#pragma unroll
    for (int off = 32; off > 0; off >>= 1)
        acc += __shfl_xor(acc, off, 64);

    if (lane == 0)
        atomicAdd(&ws[lbl], acc);
}

// --- kernel 3: sqrt bins, sum, scale (single block, 256 threads) ---
__global__ __launch_bounds__(256) void CenterLoss_finalize(
    const float* __restrict__ ws, float* __restrict__ out)
{
    const int t = threadIdx.x;
    const int lane = t & 63;

    float s = 0.0f;
    if (t < NUM_CLASSES / 4) {               // 250 threads, 1000 = 250 float4
        float4 v = reinterpret_cast<const float4*>(ws)[t];
        s = sqrtf(v.x) + sqrtf(v.y) + sqrtf(v.z) + sqrtf(v.w);
    }
#pragma unroll
    for (int off = 32; off > 0; off >>= 1)
        s += __shfl_xor(s, off, 64);

    __shared__ float partial[4];
    if (lane == 0) partial[t >> 6] = s;
    __syncthreads();
    if (t == 0)
        out[0] = (partial[0] + partial[1] + partial[2] + partial[3])
                 / (float)NUM_CLASSES;
}

extern "C" void kernel_launch(void* const* d_in, const int* in_sizes, int n_in,
                              void* d_out, int out_size, void* d_ws, size_t ws_size,
                              hipStream_t stream) {
    const float* x       = (const float*)d_in[0];
    const int*   labels  = (const int*)d_in[1];
    const float* centers = (const float*)d_in[2];
    float* out = (float*)d_out;
    float* ws  = (float*)d_ws;

    CenterLoss_zero_ws<<<1, 256, 0, stream>>>(ws);
    CenterLoss_accum<<<NROWS / 4, 256, 0, stream>>>(x, labels, centers, ws);
    CenterLoss_finalize<<<1, 256, 0, stream>>>(ws, out);
}